// Round 1
// baseline (687.821 us; speedup 1.0000x reference)
//
#include <hip/hip_runtime.h>
#include <hip/hip_bf16.h>

// DomainSpecificHeads: out[b] = (hs[b] @ W_base + b_base) @ W_heads[idx[b]] + b_heads[idx[b]]
// B=8 S=512 D=1024 V=32000 ND=8 (slot ND = default head for out-of-range ids)

#define BCNT 8
#define SLEN 512
#define DDIM 1024
#define VDIM 32000
#define NDOM 8

typedef __attribute__((ext_vector_type(4))) float f32x4;
typedef __attribute__((ext_vector_type(8))) short bf16x8;

static __device__ __forceinline__ unsigned short f2bf(float f) {
    union { float f; unsigned int u; } x; x.f = f;
    unsigned int u = x.u;
    return (unsigned short)((u + 0x7FFFu + ((u >> 16) & 1u)) >> 16);  // RNE
}

// One GEMM template: C[M x NCOLS] = A[M x 1024] * B[1024 x NCOLS] + bias
//  A_BF16:  A already bf16 (stage via global_load_lds)  else fp32 (reg-stage + convert)
//  OUT_BF16: C stored as bf16 (hidden) else fp32 (final out)
//  PER_EX:  B/bias gathered per example via domain_ids
template<bool A_BF16, bool OUT_BF16, int NCOLS, bool PER_EX>
__global__ __launch_bounds__(256)
void gemm_k(const void* __restrict__ Av, const float* __restrict__ Bbase,
            const float* __restrict__ biasBase, void* __restrict__ Cv,
            const int* __restrict__ domain_ids, int Mrows)
{
    __shared__ __align__(16) __hip_bfloat16 lds_a[128 * 64];   // A tile [128][64] bf16, linear
    __shared__ __align__(16) unsigned int   lds_b[32 * 128];   // B tile: k-pairs [kk][n], u32={bf16 k, bf16 k+1}

    const int tid  = threadIdx.x;
    const int lane = tid & 63;
    const int w    = tid >> 6;

    // bijective XCD-chunked swizzle (nwg % 8 == 0 for both launches)
    const int nwg = gridDim.x;
    const int bid = blockIdx.x;
    const int q   = nwg >> 3;
    const int sid = (bid & 7) * q + (bid >> 3);

    const int MT = Mrows >> 7;     // number of 128-row M tiles (M innermost: panel-sharing blocks adjacent)
    const int mt = sid % MT;
    const int nt = sid / MT;
    const int m0 = mt << 7;
    const int n0 = nt << 7;

    const float* Bp   = Bbase;
    const float* bias = biasBase;
    if (PER_EX) {
        const int ex  = m0 / SLEN;
        const int di  = domain_ids[ex];
        const int hid = (di >= 0 && di < NDOM) ? di : NDOM;
        Bp   = Bbase   + (size_t)hid * DDIM * (size_t)NCOLS;
        bias = biasBase + (size_t)hid * (size_t)NCOLS;
    }

    f32x4 acc[4][4];
    #pragma unroll
    for (int m = 0; m < 4; ++m)
        #pragma unroll
        for (int n = 0; n < 4; ++n)
            acc[m][n] = (f32x4)0.0f;

    const int wr = w >> 1, wc = w & 1;     // 2x2 wave grid, each wave owns 64x64
    const int lr = lane & 15, lg = lane >> 4;

    for (int kt = 0; kt < DDIM / 64; ++kt) {
        const int kbase = kt * 64;

        // ---- stage A tile [128 rows][64 k] into linear LDS ----
        if (A_BF16) {
            const __hip_bfloat16* Ab = (const __hip_bfloat16*)Av;
            #pragma unroll
            for (int i = 0; i < 4; ++i) {
                const int base_e = (i * 256 + w * 64) * 8;          // wave-uniform LDS base (elems)
                const int flat   = base_e + lane * 8;
                const int row = flat >> 6, col = flat & 63;
                const __hip_bfloat16* src = Ab + (size_t)(m0 + row) * DDIM + kbase + col;
                __builtin_amdgcn_global_load_lds(
                    (const __attribute__((address_space(1))) unsigned int*)src,
                    (__attribute__((address_space(3))) unsigned int*)(lds_a + base_e),
                    16, 0, 0);
            }
        } else {
            const float* Af = (const float*)Av;
            #pragma unroll
            for (int t = 0; t < 8; ++t) {
                const int flat = (t * 256 + tid) * 4;
                const int row = flat >> 6, col = flat & 63;
                const float4 v = *(const float4*)(Af + (size_t)(m0 + row) * DDIM + kbase + col);
                uint2 pp;
                pp.x = (unsigned int)f2bf(v.x) | ((unsigned int)f2bf(v.y) << 16);
                pp.y = (unsigned int)f2bf(v.z) | ((unsigned int)f2bf(v.w) << 16);
                *(uint2*)(lds_a + flat) = pp;
            }
        }

        // ---- stage B tile: fp32 [64][NCOLS] slab -> k-pair-packed [32][128] u32 ----
        #pragma unroll
        for (int t = 0; t < 4; ++t) {
            const int id = t * 256 + tid;
            const int kk = id >> 5;            // 0..31 (pair of k rows)
            const int n  = (id & 31) << 2;     // 0..124 step 4
            const float* b0 = Bp + (size_t)(kbase + 2 * kk) * (size_t)NCOLS + n0 + n;
            const float4 e = *(const float4*)b0;            // k even row
            const float4 o = *(const float4*)(b0 + NCOLS);  // k odd row
            uint4 pw;
            pw.x = (unsigned int)f2bf(e.x) | ((unsigned int)f2bf(o.x) << 16);
            pw.y = (unsigned int)f2bf(e.y) | ((unsigned int)f2bf(o.y) << 16);
            pw.z = (unsigned int)f2bf(e.z) | ((unsigned int)f2bf(o.z) << 16);
            pw.w = (unsigned int)f2bf(e.w) | ((unsigned int)f2bf(o.w) << 16);
            const int ns = n ^ ((kk & 4) << 2);   // 1-bit XOR: 4-way bank conflict -> 2-way (free)
            *(uint4*)&lds_b[kk * 128 + ns] = pw;
        }

        __syncthreads();

        // ---- compute: 2 k-slices of 32, 4x4 fragments per wave ----
        #pragma unroll
        for (int ks = 0; ks < 2; ++ks) {
            bf16x8 af[4], bfr[4];
            #pragma unroll
            for (int m = 0; m < 4; ++m) {
                const int row = wr * 64 + m * 16 + lr;
                const int k   = ks * 32 + lg * 8;
                af[m] = *(const bf16x8*)&lds_a[row * 64 + k];
            }
            #pragma unroll
            for (int n = 0; n < 4; ++n) {
                const int col = wc * 64 + n * 16 + lr;
                const int kkb = ks * 16 + lg * 4;
                union { unsigned int u[4]; bf16x8 v; } cvt;
                #pragma unroll
                for (int j = 0; j < 4; ++j) {
                    const int kk = kkb + j;
                    const int ns = col ^ ((kk & 4) << 2);
                    cvt.u[j] = lds_b[kk * 128 + ns];
                }
                bfr[n] = cvt.v;
            }
            #pragma unroll
            for (int m = 0; m < 4; ++m)
                #pragma unroll
                for (int n = 0; n < 4; ++n)
                    acc[m][n] = __builtin_amdgcn_mfma_f32_16x16x32_bf16(af[m], bfr[n], acc[m][n], 0, 0, 0);
        }

        __syncthreads();
    }

    // ---- epilogue: bias + store ----
    float biasv[4];
    #pragma unroll
    for (int n = 0; n < 4; ++n)
        biasv[n] = bias[n0 + wc * 64 + n * 16 + lr];

    #pragma unroll
    for (int m = 0; m < 4; ++m) {
        #pragma unroll
        for (int n = 0; n < 4; ++n) {
            const int col = n0 + wc * 64 + n * 16 + lr;
            #pragma unroll
            for (int r = 0; r < 4; ++r) {
                const int row = m0 + wr * 64 + m * 16 + lg * 4 + r;   // C/D: row=(lane>>4)*4+reg, col=lane&15
                const float val = acc[m][n][r] + biasv[n];
                if (OUT_BF16) {
                    ((unsigned short*)Cv)[(size_t)row * NCOLS + col] = f2bf(val);
                } else {
                    ((float*)Cv)[(size_t)row * NCOLS + col] = val;
                }
            }
        }
    }
}

extern "C" void kernel_launch(void* const* d_in, const int* in_sizes, int n_in,
                              void* d_out, int out_size, void* d_ws, size_t ws_size,
                              hipStream_t stream)
{
    const float* hs  = (const float*)d_in[0];   // [8,512,1024] fp32
    const int*   dom = (const int*)d_in[1];     // [8] int32
    const float* Wb  = (const float*)d_in[2];   // [1024,1024] fp32
    const float* bb  = (const float*)d_in[3];   // [1024] fp32
    const float* Wh  = (const float*)d_in[4];   // [9,1024,32000] fp32
    const float* bh  = (const float*)d_in[5];   // [9,32000] fp32
    float* out = (float*)d_out;                 // [8,512,32000] fp32
    __hip_bfloat16* hidden = (__hip_bfloat16*)d_ws;   // [4096,1024] bf16, 8 MB

    const int M = BCNT * SLEN;  // 4096

    // G1: hidden = hs @ W_base + b_base   (fp32 in, bf16 out)
    const int g1 = (M / 128) * (DDIM / 128);   // 256 blocks
    hipLaunchKernelGGL((gemm_k<false, true, DDIM, false>), dim3(g1), dim3(256), 0, stream,
                       (const void*)hs, Wb, bb, (void*)hidden, dom, M);

    // G2: out = hidden @ W_heads[eff_idx] + b_heads[eff_idx]   (bf16 A, fp32 B->bf16, fp32 out)
    const int g2 = (M / 128) * (VDIM / 128);   // 8000 blocks
    hipLaunchKernelGGL((gemm_k<true, false, VDIM, true>), dim3(g2), dim3(256), 0, stream,
                       (const void*)hidden, Wh, bh, (void*)out, dom, M);
}